// Round 10
// baseline (349.551 us; speedup 1.0000x reference)
//
#include <hip/hip_runtime.h>

// x[16,64,96,96] f32, dict[100,64,3,3] f32, coeff[256,3,3,3] f32, idx[256,3,3,3] i32
// out[16,256,96,96] f32
#define NB   16
#define CIN  64
#define HH   96
#define WW   96
#define DD   100
#define OO   256
#define NWG  (NB * HH)   // 1536 transpose blocks in prep
#define NCB  512         // conv blocks: 16 b x 32 h-chunks (3 rows each)

typedef __attribute__((ext_vector_type(8))) short  bf16x8;
typedef __attribute__((ext_vector_type(4))) float  f32x4;

// XOR swizzle on the 16B-granule bits (4-6) within a 128B (= one wp) row
#define FSWZ(wp) ((((wp) ^ ((wp) >> 3)) & 7) << 4)

static __device__ __forceinline__ unsigned short f32_to_bf16(float f) {
    unsigned int u = __float_as_uint(f);
    u += 0x7FFFu + ((u >> 16) & 1u);   // RNE
    return (unsigned short)(u >> 16);
}

// ---- fused prep:
//  blocks [0,1536): x f32 NCHW -> bf16 NHWC (x2[b][h][w][c])
//  blocks [1536,1792): W_eff = scatter(coeff,idx) @ dict, MFMA B-fragment order:
//    halfword index = (kpos*32 + otile*2 + ks)*512 + lane*8 + e;  block 1536 also zeroes zbuf
__global__ __launch_bounds__(256) void prep_kernel(
    const float* __restrict__ x, const float* __restrict__ dict,
    const float* __restrict__ coeff, const int* __restrict__ idx,
    unsigned short* __restrict__ x2, unsigned short* __restrict__ weff2,
    unsigned short* __restrict__ zbuf)
{
    __shared__ unsigned short lds[CIN * 100];
    __shared__ float wrow[DD];
    const int blk = blockIdx.x, tid = threadIdx.x;

    if (blk < NWG) {
        const int b = blk / HH, h = blk % HH;
        for (int it = 0; it < 6; ++it) {
            int i = tid + it * 256;                  // 64*24 float4 units
            int c = i / 24, w4 = i % 24;
            float4 v = *reinterpret_cast<const float4*>(
                x + (((size_t)(b * CIN + c) * HH + h) * WW + w4 * 4));
            ushort4 u;
            u.x = f32_to_bf16(v.x); u.y = f32_to_bf16(v.y);
            u.z = f32_to_bf16(v.z); u.w = f32_to_bf16(v.w);
            *reinterpret_cast<ushort4*>(&lds[c * 100 + w4 * 4]) = u;
        }
        __syncthreads();
        for (int it = 0; it < 6; ++it) {
            int i = tid + it * 256;                  // 96*16 ushort4 units
            int w = i / 16, c = (i % 16) * 4;
            ushort4 u;
            u.x = lds[(c + 0) * 100 + w];
            u.y = lds[(c + 1) * 100 + w];
            u.z = lds[(c + 2) * 100 + w];
            u.w = lds[(c + 3) * 100 + w];
            *reinterpret_cast<ushort4*>(x2 + (((size_t)(b * HH + h) * WW + w) * CIN + c)) = u;
        }
    } else {
        const int o = blk - NWG;
        if (o == 0 && tid < 8) zbuf[tid] = 0;        // 16B zero source for pads
        if (tid < DD) wrow[tid] = 0.f;
        __syncthreads();
        if (tid == 0) {                              // deterministic serial scatter
            for (int s = 0; s < 27; ++s) wrow[idx[o * 27 + s]] += coeff[o * 27 + s];
        }
        __syncthreads();
        for (int j = tid; j < 576; j += 256) {       // j = kpos*64 + c
            int kpos = j >> 6, c = j & 63;
            float s = 0.f;
            for (int d = 0; d < DD; ++d)
                s += wrow[d] * dict[d * 576 + c * 9 + kpos];
            int otile = o >> 4, ks = c >> 5;
            int lane8 = (o & 15) | (((c >> 3) & 3) << 4);
            weff2[((size_t)(kpos * 32 + otile * 2 + ks)) * 512 + lane8 * 8 + (c & 7)]
                = f32_to_bf16(s);
        }
    }
}

// ---- conv: persistent block = (b, h0..h0+2); 8 waves 2(w-half) x 4(o-quarter).
// R6 wave shape (a-read feeds 4 MFMAs) + row persistence with 4-slot LDS ring.
// Depth-2 B banks (32 regs) keep unified reg use ~120 < 128 (no spill at 4 w/EU).
// Per row: 1 barrier; stage ONE new row right after it (latency hides under k-loop).
__global__ __launch_bounds__(512, 4) void conv_kernel(
    const unsigned short* __restrict__ x2,     // [16][96][96][64] bf16 NHWC
    const unsigned short* __restrict__ weff2,  // fragment-ordered, 288KB (L2-resident)
    const unsigned short* __restrict__ zbuf,   // 16B of zeros
    float* __restrict__ out)                   // [16][256][96][96] f32
{
    __shared__ unsigned short xs[4 * 98 * 64]; // 4 row slots, wp in [0,98), 50176 B

    const int wg  = blockIdx.x;
    const int swz = (wg & 7) * (NCB / 8) + (wg >> 3);  // XCD-bijective (512%8==0)
    const int b = swz / 32, h0 = (swz % 32) * 3;
    const int tid = threadIdx.x;
    const int lane = tid & 63, wid = tid >> 6;
    const int wm = wid >> 2, wn = wid & 3;     // wm: w-half, wn: o-quarter
    const int l15 = lane & 15;

    char* xsb = reinterpret_cast<char*>(xs);
    const char* x2b = reinterpret_cast<const char*>(x2) + (size_t)b * HH * WW * 128;
    const char* zbp = reinterpret_cast<const char*>(zbuf);

    // stage one input row hp into ring slot (hp+1)&3 (784 chunks of 16B)
    auto stage_row = [&](int hp) {
        const int sl = (hp + 1) & 3;
#pragma unroll
        for (int it = 0; it < 2; ++it) {
            int chunk = tid + it * 512;
            if (chunk < 784) {
                int wp = chunk >> 3, gb = (chunk & 7) << 4;
                const char* src = (wp >= 1 && wp <= 96 && hp >= 0 && hp < HH)
                    ? x2b + ((size_t)(hp * WW + wp - 1) * 128 + (gb ^ FSWZ(wp)))
                    : zbp;
                __builtin_amdgcn_global_load_lds(
                    (const __attribute__((address_space(1))) void*)src,
                    (__attribute__((address_space(3))) void*)(xsb + sl * 12544 + chunk * 16),
                    16, 0, 0);
            }
        }
    };

    // ---- B-fragment prologue: banks for steps 0,1 (fly under prologue staging) ----
    const unsigned short* wbase = weff2 + (size_t)(wn * 8) * 512 + lane * 8;
    bf16x8 bA[4], bB[4];
#pragma unroll
    for (int n = 0; n < 4; ++n)
        bA[n] = *reinterpret_cast<const bf16x8*>(wbase + (n * 2 + 0) * 512);
#pragma unroll
    for (int n = 0; n < 4; ++n)
        bB[n] = *reinterpret_cast<const bf16x8*>(wbase + (n * 2 + 1) * 512);

    // ---- prologue: stage rows h0-1, h0, h0+1 (cold start once per 3 rows) ----
    stage_row(h0 - 1);
    stage_row(h0);
    stage_row(h0 + 1);

    const int wb16 = wm * 48 + l15;

    for (int hi = 0; hi < 3; ++hi) {
        const int h = h0 + hi;
        __syncthreads();                       // slots for this h ready (vmcnt drained)
        if (hi < 2) stage_row(h + 2);          // prefetch next row under this k-loop

        f32x4 acc[3][4];
#pragma unroll
        for (int m = 0; m < 3; ++m)
#pragma unroll
            for (int n = 0; n < 4; ++n)
                acc[m][n] = (f32x4){0.f, 0.f, 0.f, 0.f};

        // LDS bases of rows h-1, h, h+1: slot(r) = (r+1)&3
        int sb0 = ((h + 0) & 3) * 12544;
        int sb1 = ((h + 1) & 3) * 12544;
        int sb2 = ((h + 2) & 3) * 12544;

        // ---- 18 half-steps: s = (kpos=s>>1, ks=s&1); banks by parity, prefetch +2 ----
#pragma unroll
        for (int s = 0; s < 18; ++s) {
            const int kpos = s >> 1, ks = s & 1;
            const int kh = kpos / 3, dw = kpos % 3;
            const int sbase = (kh == 0) ? sb0 : (kh == 1) ? sb1 : sb2;
            const int cb = (ks * 32 + (lane >> 4) * 8) * 2;   // byte offset of c
            bf16x8 a[3];
#pragma unroll
            for (int m = 0; m < 3; ++m) {
                int wpos = wb16 + m * 16 + dw;
                a[m] = *reinterpret_cast<const bf16x8*>(
                    xsb + sbase + wpos * 128 + (cb ^ FSWZ(wpos)));
            }
#pragma unroll
            for (int m = 0; m < 3; ++m)
#pragma unroll
                for (int n = 0; n < 4; ++n)
                    acc[m][n] = __builtin_amdgcn_mfma_f32_16x16x32_bf16(
                        a[m], (s & 1) ? bB[n] : bA[n], acc[m][n], 0, 0, 0);
            if (s < 16) {                      // reload this parity's bank with s+2
                const int s2 = s + 2;
                const int off = (s2 >> 1) * 32 + (s2 & 1);
#pragma unroll
                for (int n = 0; n < 4; ++n) {
                    bf16x8 v = *reinterpret_cast<const bf16x8*>(
                        wbase + (off + n * 2) * 512);
                    if ((s & 1) == 0) bA[n] = v; else bB[n] = v;
                }
            }
        }

        // re-arm banks for next row's steps 0,1 (hides under epilogue stores)
        if (hi < 2) {
#pragma unroll
            for (int n = 0; n < 4; ++n)
                bA[n] = *reinterpret_cast<const bf16x8*>(wbase + (n * 2 + 0) * 512);
#pragma unroll
            for (int n = 0; n < 4; ++n)
                bB[n] = *reinterpret_cast<const bf16x8*>(wbase + (n * 2 + 1) * 512);
        }

        // ---- epilogue: plain float4 stores ----
        float* outb = out + ((size_t)b * OO * HH + h) * WW;
#pragma unroll
        for (int m = 0; m < 3; ++m)
#pragma unroll
            for (int n = 0; n < 4; ++n) {
                int o = wn * 64 + n * 16 + l15;
                int w = wm * 48 + m * 16 + (lane >> 4) * 4;
                *reinterpret_cast<f32x4*>(outb + (size_t)o * HH * WW + w) = acc[m][n];
            }
    }
}

extern "C" void kernel_launch(void* const* d_in, const int* in_sizes, int n_in,
                              void* d_out, int out_size, void* d_ws, size_t ws_size,
                              hipStream_t stream) {
    const float* x     = (const float*)d_in[0];
    const float* dict  = (const float*)d_in[1];
    const float* coeff = (const float*)d_in[2];
    const int*   idx   = (const int*)d_in[3];
    float* out = (float*)d_out;

    char* ws = (char*)d_ws;
    unsigned short* weff2 = (unsigned short*)ws;               // 294912 B
    unsigned short* zbuf  = (unsigned short*)(ws + 294912);    // 16 B zeros
    unsigned short* x2    = (unsigned short*)(ws + 1048576);   // 18874368 B

    prep_kernel<<<NWG + OO, 256, 0, stream>>>(x, dict, coeff, idx, x2, weff2, zbuf);
    conv_kernel<<<NCB, 512, 0, stream>>>(x2, weff2, zbuf, out);
}

// Round 11
// 139.980 us; speedup vs baseline: 2.4971x; 2.4971x over previous
//
#include <hip/hip_runtime.h>

// x[16,64,96,96] f32, dict[100,64,3,3] f32, coeff[256,3,3,3] f32, idx[256,3,3,3] i32
// out[16,256,96,96] f32
#define NB   16
#define CIN  64
#define HH   96
#define WW   96
#define DD   100
#define OO   256
#define NWG  (NB * HH)   // 1536 transpose blocks in prep
#define NCV  1536        // conv blocks: 16 b x 48 row-pairs x 2 o-halves

typedef __attribute__((ext_vector_type(8))) short  bf16x8;
typedef __attribute__((ext_vector_type(4))) float  f32x4;

// XOR swizzle on the 16B-granule bits (4-6) within a 128B (= one wp) row
#define FSWZ(wp) ((((wp) ^ ((wp) >> 3)) & 7) << 4)

static __device__ __forceinline__ unsigned short f32_to_bf16(float f) {
    unsigned int u = __float_as_uint(f);
    u += 0x7FFFu + ((u >> 16) & 1u);   // RNE
    return (unsigned short)(u >> 16);
}

// ---- fused prep:
//  blocks [0,1536): x f32 NCHW -> bf16 NHWC (x2[b][h][w][c])
//  blocks [1536,1792): W_eff = scatter(coeff,idx) @ dict, MFMA B-fragment order:
//    halfword index = (kpos*32 + otile*2 + ks)*512 + lane*8 + e;  block 1536 also zeroes zbuf
__global__ __launch_bounds__(256) void prep_kernel(
    const float* __restrict__ x, const float* __restrict__ dict,
    const float* __restrict__ coeff, const int* __restrict__ idx,
    unsigned short* __restrict__ x2, unsigned short* __restrict__ weff2,
    unsigned short* __restrict__ zbuf)
{
    __shared__ unsigned short lds[CIN * 100];
    __shared__ float wrow[DD];
    const int blk = blockIdx.x, tid = threadIdx.x;

    if (blk < NWG) {
        const int b = blk / HH, h = blk % HH;
        for (int it = 0; it < 6; ++it) {
            int i = tid + it * 256;                  // 64*24 float4 units
            int c = i / 24, w4 = i % 24;
            float4 v = *reinterpret_cast<const float4*>(
                x + (((size_t)(b * CIN + c) * HH + h) * WW + w4 * 4));
            ushort4 u;
            u.x = f32_to_bf16(v.x); u.y = f32_to_bf16(v.y);
            u.z = f32_to_bf16(v.z); u.w = f32_to_bf16(v.w);
            *reinterpret_cast<ushort4*>(&lds[c * 100 + w4 * 4]) = u;
        }
        __syncthreads();
        for (int it = 0; it < 6; ++it) {
            int i = tid + it * 256;                  // 96*16 ushort4 units
            int w = i / 16, c = (i % 16) * 4;
            ushort4 u;
            u.x = lds[(c + 0) * 100 + w];
            u.y = lds[(c + 1) * 100 + w];
            u.z = lds[(c + 2) * 100 + w];
            u.w = lds[(c + 3) * 100 + w];
            *reinterpret_cast<ushort4*>(x2 + (((size_t)(b * HH + h) * WW + w) * CIN + c)) = u;
        }
    } else {
        const int o = blk - NWG;
        if (o == 0 && tid < 8) zbuf[tid] = 0;        // 16B zero source for pads
        if (tid < DD) wrow[tid] = 0.f;
        __syncthreads();
        if (tid == 0) {                              // deterministic serial scatter
            for (int s = 0; s < 27; ++s) wrow[idx[o * 27 + s]] += coeff[o * 27 + s];
        }
        __syncthreads();
        for (int j = tid; j < 576; j += 256) {       // j = kpos*64 + c
            int kpos = j >> 6, c = j & 63;
            float s = 0.f;
            for (int d = 0; d < DD; ++d)
                s += wrow[d] * dict[d * 576 + c * 9 + kpos];
            int otile = o >> 4, ks = c >> 5;
            int lane8 = (o & 15) | (((c >> 3) & 3) << 4);
            weff2[((size_t)(kpos * 32 + otile * 2 + ks)) * 512 + lane8 * 8 + (c & 7)]
                = f32_to_bf16(s);
        }
    }
}

// ---- conv: block = (b, rows h0..h0+1, o-half of 128); 8 waves 2(wm) x 4(wn).
// Per wave: m=3 w-frags x n=2 o-frags x q=2 rows. B-frag feeds 6 MFMAs (3m x 2q),
// B-L2 traffic 884 -> 221 MB vs R6. Straight-line, fully unrolled, 1 barrier.
// Regs: acc 48 + a 24 + banks 16 + addr ~20  ->  ~108 < 128 cap (no spill).
__global__ __launch_bounds__(512, 4) void conv_kernel(
    const unsigned short* __restrict__ x2,     // [16][96][96][64] bf16 NHWC
    const unsigned short* __restrict__ weff2,  // fragment-ordered, 288KB (L2-resident)
    const unsigned short* __restrict__ zbuf,   // 16B of zeros
    float* __restrict__ out)                   // [16][256][96][96] f32
{
    __shared__ unsigned short xs[4 * 98 * 64]; // rows h0-1..h0+2, wp in [0,98), 50176 B

    const int wg  = blockIdx.x;
    const int swz = (wg & 7) * (NCV / 8) + (wg >> 3);  // XCD-bijective (1536%8==0)
    const int oh = swz & 1;                    // o-half fastest: both halves share rows in L2
    const int rb = swz >> 1;                   // 0..767
    const int b = rb / 48, h0 = (rb % 48) * 2;
    const int tid = threadIdx.x;
    const int lane = tid & 63, wid = tid >> 6;
    const int wm = wid >> 2, wn = wid & 3;     // wm: w-half, wn: o-eighth-pair
    const int l15 = lane & 15;

    char* xsb = reinterpret_cast<char*>(xs);
    const char* x2b = reinterpret_cast<const char*>(x2) + (size_t)b * HH * WW * 128;
    const char* zbp = reinterpret_cast<const char*>(zbuf);

    // ---- B-fragment prologue: banks for steps 0,1 (fly under staging) ----
    // otile(n) = oh*8 + wn*2 + n; frag = kpos*32 + otile*2 + ks
    const unsigned short* wbase = weff2 + (size_t)((oh * 8 + wn * 2) * 2) * 512 + lane * 8;
    bf16x8 bA[2], bB[2];
#pragma unroll
    for (int n = 0; n < 2; ++n)
        bA[n] = *reinterpret_cast<const bf16x8*>(wbase + (n * 2 + 0) * 512);
#pragma unroll
    for (int n = 0; n < 2; ++n)
        bB[n] = *reinterpret_cast<const bf16x8*>(wbase + (n * 2 + 1) * 512);

    // ---- stage rows h0-1 .. h0+2 via global_load_lds, source pre-swizzled ----
#pragma unroll
    for (int it = 0; it < 7; ++it) {
        int chunk = tid + it * 512;            // 4*98*8 = 3136 chunks of 16B
        if (chunk < 3136) {
            int r = chunk / 784, rem = chunk % 784;
            int wp = rem >> 3, gb = (rem & 7) << 4;
            int hp = h0 - 1 + r;
            const char* src = (wp >= 1 && wp <= 96 && hp >= 0 && hp < HH)
                ? x2b + ((size_t)(hp * WW + wp - 1) * 128 + (gb ^ FSWZ(wp)))
                : zbp;
            __builtin_amdgcn_global_load_lds(
                (const __attribute__((address_space(1))) void*)src,
                (__attribute__((address_space(3))) void*)(xsb + chunk * 16),
                16, 0, 0);
        }
    }

    f32x4 acc[2][3][2];
#pragma unroll
    for (int q = 0; q < 2; ++q)
#pragma unroll
        for (int m = 0; m < 3; ++m)
#pragma unroll
            for (int n = 0; n < 2; ++n)
                acc[q][m][n] = (f32x4){0.f, 0.f, 0.f, 0.f};

    __syncthreads();                           // xs staged (only barrier)

    const int wb16 = wm * 48 + l15;

    // ---- 18 half-steps: s = (kpos=s>>1, ks=s&1); banks by parity, prefetch +2 ----
#pragma unroll
    for (int s = 0; s < 18; ++s) {
        const int kpos = s >> 1, ks = s & 1;
        const int kh = kpos / 3, dw = kpos % 3;
        const int cb = (ks * 32 + (lane >> 4) * 8) * 2;   // byte offset of c
        bf16x8 a[2][3];
#pragma unroll
        for (int m = 0; m < 3; ++m) {
            int wpos = wb16 + m * 16 + dw;
            int rowoff = wpos * 128 + (cb ^ FSWZ(wpos));
#pragma unroll
            for (int q = 0; q < 2; ++q)
                a[q][m] = *reinterpret_cast<const bf16x8*>(
                    xsb + (kh + q) * 12544 + rowoff);
        }
#pragma unroll
        for (int q = 0; q < 2; ++q)
#pragma unroll
            for (int m = 0; m < 3; ++m)
#pragma unroll
                for (int n = 0; n < 2; ++n)
                    acc[q][m][n] = __builtin_amdgcn_mfma_f32_16x16x32_bf16(
                        a[q][m], (s & 1) ? bB[n] : bA[n], acc[q][m][n], 0, 0, 0);
        if (s < 16) {                          // reload this parity's bank with s+2
            const int s2 = s + 2;
            const int off = (s2 >> 1) * 32 + (s2 & 1);
#pragma unroll
            for (int n = 0; n < 2; ++n) {
                bf16x8 v = *reinterpret_cast<const bf16x8*>(wbase + (off + n * 2) * 512);
                if ((s & 1) == 0) bA[n] = v; else bB[n] = v;
            }
        }
    }

    // ---- epilogue: plain float4 stores ----
#pragma unroll
    for (int q = 0; q < 2; ++q)
#pragma unroll
        for (int m = 0; m < 3; ++m)
#pragma unroll
            for (int n = 0; n < 2; ++n) {
                int o = oh * 128 + wn * 32 + n * 16 + l15;
                int w = wm * 48 + m * 16 + (lane >> 4) * 4;
                *reinterpret_cast<f32x4*>(
                    out + (((size_t)(b * OO + o) * HH + h0 + q) * WW + w))
                    = acc[q][m][n];
            }
}

extern "C" void kernel_launch(void* const* d_in, const int* in_sizes, int n_in,
                              void* d_out, int out_size, void* d_ws, size_t ws_size,
                              hipStream_t stream) {
    const float* x     = (const float*)d_in[0];
    const float* dict  = (const float*)d_in[1];
    const float* coeff = (const float*)d_in[2];
    const int*   idx   = (const int*)d_in[3];
    float* out = (float*)d_out;

    char* ws = (char*)d_ws;
    unsigned short* weff2 = (unsigned short*)ws;               // 294912 B
    unsigned short* zbuf  = (unsigned short*)(ws + 294912);    // 16 B zeros
    unsigned short* x2    = (unsigned short*)(ws + 1048576);   // 18874368 B

    prep_kernel<<<NWG + OO, 256, 0, stream>>>(x, dict, coeff, idx, x2, weff2, zbuf);
    conv_kernel<<<NCV, 512, 0, stream>>>(x2, weff2, zbuf, out);
}

// Round 12
// 135.150 us; speedup vs baseline: 2.5864x; 1.0357x over previous
//
#include <hip/hip_runtime.h>

// x[16,64,96,96] f32, dict[100,64,3,3] f32, coeff[256,3,3,3] f32, idx[256,3,3,3] i32
// out[16,256,96,96] f32
#define NB   16
#define CIN  64
#define HH   96
#define WW   96
#define DD   100
#define OO   256
#define NWG  (NB * HH)        // 1536: transpose blocks in prep, conv blocks (1 row each)

typedef __attribute__((ext_vector_type(8))) short  bf16x8;
typedef __attribute__((ext_vector_type(4))) float  f32x4;

// XOR swizzle on the 16B-granule bits (4-6) within a 128B (= one wp) row
#define FSWZ(wp) ((((wp) ^ ((wp) >> 3)) & 7) << 4)

static __device__ __forceinline__ unsigned short f32_to_bf16(float f) {
    unsigned int u = __float_as_uint(f);
    u += 0x7FFFu + ((u >> 16) & 1u);   // RNE
    return (unsigned short)(u >> 16);
}

// ---- fused prep:
//  blocks [0,1536): x f32 NCHW -> bf16 NHWC (x2[b][h][w][c])
//  blocks [1536,1792): W_eff = scatter(coeff,idx) @ dict, MFMA B-fragment order:
//    halfword index = (kpos*32 + otile*2 + ks)*512 + lane*8 + e;  block 1536 also zeroes zbuf
__global__ __launch_bounds__(256) void prep_kernel(
    const float* __restrict__ x, const float* __restrict__ dict,
    const float* __restrict__ coeff, const int* __restrict__ idx,
    unsigned short* __restrict__ x2, unsigned short* __restrict__ weff2,
    unsigned short* __restrict__ zbuf)
{
    __shared__ unsigned short lds[CIN * 100];
    __shared__ float wrow[DD];
    const int blk = blockIdx.x, tid = threadIdx.x;

    if (blk < NWG) {
        const int b = blk / HH, h = blk % HH;
        for (int it = 0; it < 6; ++it) {
            int i = tid + it * 256;                  // 64*24 float4 units
            int c = i / 24, w4 = i % 24;
            float4 v = *reinterpret_cast<const float4*>(
                x + (((size_t)(b * CIN + c) * HH + h) * WW + w4 * 4));
            ushort4 u;
            u.x = f32_to_bf16(v.x); u.y = f32_to_bf16(v.y);
            u.z = f32_to_bf16(v.z); u.w = f32_to_bf16(v.w);
            *reinterpret_cast<ushort4*>(&lds[c * 100 + w4 * 4]) = u;
        }
        __syncthreads();
        for (int it = 0; it < 6; ++it) {
            int i = tid + it * 256;                  // 96*16 ushort4 units
            int w = i / 16, c = (i % 16) * 4;
            ushort4 u;
            u.x = lds[(c + 0) * 100 + w];
            u.y = lds[(c + 1) * 100 + w];
            u.z = lds[(c + 2) * 100 + w];
            u.w = lds[(c + 3) * 100 + w];
            *reinterpret_cast<ushort4*>(x2 + (((size_t)(b * HH + h) * WW + w) * CIN + c)) = u;
        }
    } else {
        const int o = blk - NWG;
        if (o == 0 && tid < 8) zbuf[tid] = 0;        // 16B zero source for pads
        if (tid < DD) wrow[tid] = 0.f;
        __syncthreads();
        if (tid == 0) {                              // deterministic serial scatter
            for (int s = 0; s < 27; ++s) wrow[idx[o * 27 + s]] += coeff[o * 27 + s];
        }
        __syncthreads();
        for (int j = tid; j < 576; j += 256) {       // j = kpos*64 + c
            int kpos = j >> 6, c = j & 63;
            float s = 0.f;
            for (int d = 0; d < DD; ++d)
                s += wrow[d] * dict[d * 576 + c * 9 + kpos];
            int otile = o >> 4, ks = c >> 5;
            int lane8 = (o & 15) | (((c >> 3) & 3) << 4);
            weff2[((size_t)(kpos * 32 + otile * 2 + ks)) * 512 + lane8 * 8 + (c & 7)]
                = f32_to_bf16(s);
        }
    }
}

// ---- conv: block = (b,h) output row; 8 waves 2(w-half) x 4(o-quarter).
// R6 structure + WAVE-STAGGERED k-loop: wave wid starts at half-step s0 = wid*2
// and rotates through all 18 (accumulation commutes; per-thread order fixed ->
// deterministic). De-phases the 16 resident waves so ds_read stalls of one wave
// hide under MFMAs of another. setprio(1) around MFMA clusters (role-diversity
// now exists). Registers identical to R6 (~112 unified, no spill).
__global__ __launch_bounds__(512, 4) void conv_kernel(
    const unsigned short* __restrict__ x2,     // [16][96][96][64] bf16 NHWC
    const unsigned short* __restrict__ weff2,  // fragment-ordered, 288KB
    const unsigned short* __restrict__ zbuf,   // 16B of zeros
    float* __restrict__ out)                   // [16][256][96][96] f32
{
    __shared__ unsigned short xs[3 * 98 * 64]; // 3 rows, wp in [0,98), 37632 B

    const int wg  = blockIdx.x;
    const int swz = (wg & 7) * (NWG / 8) + (wg >> 3);  // XCD-bijective (1536%8==0)
    const int b = swz / HH, h = swz % HH;
    const int tid = threadIdx.x;
    const int lane = tid & 63, wid = tid >> 6;
    const int wm = wid >> 2, wn = wid & 3;     // wm: w-half, wn: o-quarter
    const int l15 = lane & 15;
    const int s0 = wid * 2;                    // stagger: even, so ks parity = i&1

    char* xsb = reinterpret_cast<char*>(xs);

    // ---- B-fragment prologue: banks for local steps 0..3 (fly under staging) ----
    const unsigned short* wbase = weff2 + (size_t)(wn * 8) * 512 + lane * 8;
    bf16x8 bfr[4][4];
#pragma unroll
    for (int j = 0; j < 4; ++j) {
        int gs = s0 + j; if (gs >= 18) gs -= 18;
        const int off = (gs >> 1) * 32 + (gs & 1);
#pragma unroll
        for (int n = 0; n < 4; ++n)
            bfr[j][n] = *reinterpret_cast<const bf16x8*>(wbase + (off + n * 2) * 512);
    }

    // ---- stage rows h-1..h+1 via global_load_lds, source pre-swizzled ----
    const char* x2b = reinterpret_cast<const char*>(x2) + (size_t)b * HH * WW * 128;
#pragma unroll
    for (int it = 0; it < 5; ++it) {
        int chunk = tid + it * 512;            // 3*98*8 = 2352 chunks of 16B
        if (chunk < 2352) {
            int r = chunk / 784, rem = chunk % 784;
            int wp = rem >> 3, gb = (rem & 7) << 4;
            int hp = h - 1 + r;
            const char* src;
            if (wp >= 1 && wp <= 96 && hp >= 0 && hp < HH)
                src = x2b + ((size_t)(hp * WW + wp - 1) * 128 + (gb ^ FSWZ(wp)));
            else
                src = reinterpret_cast<const char*>(zbuf);
            __builtin_amdgcn_global_load_lds(
                (const __attribute__((address_space(1))) void*)src,
                (__attribute__((address_space(3))) void*)(xsb + chunk * 16),
                16, 0, 0);
        }
    }

    f32x4 acc[3][4];
#pragma unroll
    for (int m = 0; m < 3; ++m)
#pragma unroll
        for (int n = 0; n < 4; ++n)
            acc[m][n] = (f32x4){0.f, 0.f, 0.f, 0.f};

    __syncthreads();                           // xs staged (only barrier)

    const int wb16 = wm * 48 + l15;

    // ---- 18 staggered half-steps: local i -> global gs = (s0+i)%18 ----
#pragma unroll
    for (int i = 0; i < 18; ++i) {
        int gs = s0 + i; if (gs >= 18) gs -= 18;       // wave-uniform
        const int kpos = gs >> 1;
        const int kh = (kpos >= 6) ? 2 : (kpos >= 3) ? 1 : 0;   // wave-uniform
        const int dw = kpos - kh * 3;
        const int sbase = kh * 12544;
        const int ks = i & 1;                          // = gs&1 (s0 even, 18 even)
        const int cb = (ks * 32 + (lane >> 4) * 8) * 2;
        bf16x8 a[3];
#pragma unroll
        for (int m = 0; m < 3; ++m) {
            int wpos = wb16 + m * 16 + dw;
            a[m] = *reinterpret_cast<const bf16x8*>(
                xsb + sbase + wpos * 128 + (cb ^ FSWZ(wpos)));
        }
        __builtin_amdgcn_s_setprio(1);
#pragma unroll
        for (int m = 0; m < 3; ++m)
#pragma unroll
            for (int n = 0; n < 4; ++n)
                acc[m][n] = __builtin_amdgcn_mfma_f32_16x16x32_bf16(
                    a[m], bfr[i & 3][n], acc[m][n], 0, 0, 0);
        __builtin_amdgcn_s_setprio(0);
        if (i < 14) {                          // reload this bank with local step i+4
            int gs4 = s0 + i + 4; if (gs4 >= 18) gs4 -= 18;
            const int off = (gs4 >> 1) * 32 + (gs4 & 1);
#pragma unroll
            for (int n = 0; n < 4; ++n)
                bfr[i & 3][n] = *reinterpret_cast<const bf16x8*>(
                    wbase + (off + n * 2) * 512);
        }
    }

    // ---- epilogue: plain float4 stores ----
#pragma unroll
    for (int m = 0; m < 3; ++m)
#pragma unroll
        for (int n = 0; n < 4; ++n) {
            int o = wn * 64 + n * 16 + l15;
            int w = wm * 48 + m * 16 + (lane >> 4) * 4;
            *reinterpret_cast<f32x4*>(
                out + (((size_t)(b * OO + o) * HH + h) * WW + w)) = acc[m][n];
        }
}

extern "C" void kernel_launch(void* const* d_in, const int* in_sizes, int n_in,
                              void* d_out, int out_size, void* d_ws, size_t ws_size,
                              hipStream_t stream) {
    const float* x     = (const float*)d_in[0];
    const float* dict  = (const float*)d_in[1];
    const float* coeff = (const float*)d_in[2];
    const int*   idx   = (const int*)d_in[3];
    float* out = (float*)d_out;

    char* ws = (char*)d_ws;
    unsigned short* weff2 = (unsigned short*)ws;               // 294912 B
    unsigned short* zbuf  = (unsigned short*)(ws + 294912);    // 16 B zeros
    unsigned short* x2    = (unsigned short*)(ws + 1048576);   // 18874368 B

    prep_kernel<<<NWG + OO, 256, 0, stream>>>(x, dict, coeff, idx, x2, weff2, zbuf);
    conv_kernel<<<NWG, 512, 0, stream>>>(x2, weff2, zbuf, out);
}

// Round 13
// 80.149 us; speedup vs baseline: 4.3613x; 1.6862x over previous
//
#include <hip/hip_runtime.h>

// x[16,64,96,96] f32, dict[100,64,3,3] f32, coeff[256,3,3,3] f32, idx[256,3,3,3] i32
// out[16,256,96,96] f32
#define NB   16
#define CIN  64
#define HH   96
#define WW   96
#define DD   100
#define OO   256
#define NWG  (NB * HH)       // 1536 transpose blocks in prep
#define NCV  (NB * HH * 2)   // 3072 conv blocks: (b, h, w-half), 256 threads each
#define WPAD 50              // wp slots per row: w in [ws-1, ws+48]

typedef __attribute__((ext_vector_type(8))) short  bf16x8;
typedef __attribute__((ext_vector_type(4))) float  f32x4;

// XOR swizzle on the 16B-granule bits (4-6) within a 128B (= one wp) row
#define FSWZ(wp) ((((wp) ^ ((wp) >> 3)) & 7) << 4)

static __device__ __forceinline__ unsigned short f32_to_bf16(float f) {
    unsigned int u = __float_as_uint(f);
    u += 0x7FFFu + ((u >> 16) & 1u);   // RNE
    return (unsigned short)(u >> 16);
}

// ---- fused prep:
//  blocks [0,1536): x f32 NCHW -> bf16 NHWC (x2[b][h][w][c])
//  blocks [1536,1792): W_eff = scatter(coeff,idx) @ dict, MFMA B-fragment order:
//    halfword index = (kpos*32 + otile*2 + ks)*512 + lane*8 + e;  block 1536 also zeroes zbuf
__global__ __launch_bounds__(256) void prep_kernel(
    const float* __restrict__ x, const float* __restrict__ dict,
    const float* __restrict__ coeff, const int* __restrict__ idx,
    unsigned short* __restrict__ x2, unsigned short* __restrict__ weff2,
    unsigned short* __restrict__ zbuf)
{
    __shared__ unsigned short lds[CIN * 100];
    __shared__ float wrow[DD];
    const int blk = blockIdx.x, tid = threadIdx.x;

    if (blk < NWG) {
        const int b = blk / HH, h = blk % HH;
        for (int it = 0; it < 6; ++it) {
            int i = tid + it * 256;                  // 64*24 float4 units
            int c = i / 24, w4 = i % 24;
            float4 v = *reinterpret_cast<const float4*>(
                x + (((size_t)(b * CIN + c) * HH + h) * WW + w4 * 4));
            ushort4 u;
            u.x = f32_to_bf16(v.x); u.y = f32_to_bf16(v.y);
            u.z = f32_to_bf16(v.z); u.w = f32_to_bf16(v.w);
            *reinterpret_cast<ushort4*>(&lds[c * 100 + w4 * 4]) = u;
        }
        __syncthreads();
        for (int it = 0; it < 6; ++it) {
            int i = tid + it * 256;                  // 96*16 ushort4 units
            int w = i / 16, c = (i % 16) * 4;
            ushort4 u;
            u.x = lds[(c + 0) * 100 + w];
            u.y = lds[(c + 1) * 100 + w];
            u.z = lds[(c + 2) * 100 + w];
            u.w = lds[(c + 3) * 100 + w];
            *reinterpret_cast<ushort4*>(x2 + (((size_t)(b * HH + h) * WW + w) * CIN + c)) = u;
        }
    } else {
        const int o = blk - NWG;
        if (o == 0 && tid < 8) zbuf[tid] = 0;        // 16B zero source for pads
        if (tid < DD) wrow[tid] = 0.f;
        __syncthreads();
        if (tid == 0) {                              // deterministic serial scatter
            for (int s = 0; s < 27; ++s) wrow[idx[o * 27 + s]] += coeff[o * 27 + s];
        }
        __syncthreads();
        for (int j = tid; j < 576; j += 256) {       // j = kpos*64 + c
            int kpos = j >> 6, c = j & 63;
            float s = 0.f;
            for (int d = 0; d < DD; ++d)
                s += wrow[d] * dict[d * 576 + c * 9 + kpos];
            int otile = o >> 4, ks = c >> 5;
            int lane8 = (o & 15) | (((c >> 3) & 3) << 4);
            weff2[((size_t)(kpos * 32 + otile * 2 + ks)) * 512 + lane8 * 8 + (c & 7)]
                = f32_to_bf16(s);
        }
    }
}

// ---- conv: block = (b, h, w-half of 48); 256 threads = 4 waves = 4 o-quarters.
// R6's exact wave shape (m=3, n=4, depth-4 B banks, static unrolled k-loop) in
// 4-wave blocks -> 4 independent barrier domains per CU (LDS 19.2KB, regs ~112):
// block-level de-phasing hides staging latency without runtime schedule state.
__global__ __launch_bounds__(256, 4) void conv_kernel(
    const unsigned short* __restrict__ x2,     // [16][96][96][64] bf16 NHWC
    const unsigned short* __restrict__ weff2,  // fragment-ordered, 288KB (L2-resident)
    const unsigned short* __restrict__ zbuf,   // 16B of zeros
    float* __restrict__ out)                   // [16][256][96][96] f32
{
    __shared__ unsigned short xs[3 * WPAD * 64]; // 3 rows x 50 wp x 64c, 19200 B

    const int wg  = blockIdx.x;
    const int swz = (wg & 7) * (NCV / 8) + (wg >> 3);  // XCD-bijective (3072%8==0)
    const int b = swz / 192, rem = swz % 192;
    const int h = rem >> 1, ws = (rem & 1) * 48;
    const int tid = threadIdx.x;
    const int lane = tid & 63, wn = tid >> 6;          // wn = o-quarter
    const int l15 = lane & 15;

    char* xsb = reinterpret_cast<char*>(xs);
    const char* x2b = reinterpret_cast<const char*>(x2) + (size_t)b * HH * WW * 128;
    const char* zbp = reinterpret_cast<const char*>(zbuf);

    // ---- B-fragment prologue: banks for steps 0..3 (fly under staging) ----
    const unsigned short* wbase = weff2 + (size_t)(wn * 8) * 512 + lane * 8;
    bf16x8 bfr[4][4];
#pragma unroll
    for (int s = 0; s < 4; ++s)
#pragma unroll
        for (int n = 0; n < 4; ++n)
            bfr[s][n] = *reinterpret_cast<const bf16x8*>(
                wbase + (((s >> 1) * 32) + n * 2 + (s & 1)) * 512);

    // ---- stage rows h-1..h+1, wp in [0,50) (global w = ws-1+wp) ----
#pragma unroll
    for (int it = 0; it < 5; ++it) {
        int chunk = tid + it * 256;            // 3*50*8 = 1200 chunks of 16B
        if (chunk < 1200) {
            int r = chunk / 400, rem2 = chunk % 400;
            int wp = rem2 >> 3, gb = (rem2 & 7) << 4;
            int hp = h - 1 + r, w = ws - 1 + wp;
            const char* src = (w >= 0 && w < WW && hp >= 0 && hp < HH)
                ? x2b + ((size_t)(hp * WW + w) * 128 + (gb ^ FSWZ(wp)))
                : zbp;
            __builtin_amdgcn_global_load_lds(
                (const __attribute__((address_space(1))) void*)src,
                (__attribute__((address_space(3))) void*)(xsb + chunk * 16),
                16, 0, 0);
        }
    }

    f32x4 acc[3][4];
#pragma unroll
    for (int m = 0; m < 3; ++m)
#pragma unroll
        for (int n = 0; n < 4; ++n)
            acc[m][n] = (f32x4){0.f, 0.f, 0.f, 0.f};

    __syncthreads();                           // xs staged (only barrier)

    // ---- 18 half-steps: s = (kpos=s>>1, ks=s&1); bank = s&3, prefetch +4 ----
#pragma unroll
    for (int s = 0; s < 18; ++s) {
        const int kpos = s >> 1, ks = s & 1;
        const int kh = kpos / 3, dw = kpos % 3;
        const int cb = (ks * 32 + (lane >> 4) * 8) * 2;   // byte offset of c
        bf16x8 a[3];
#pragma unroll
        for (int m = 0; m < 3; ++m) {
            int wpos = m * 16 + l15 + dw;      // local wp (0 maps to global ws-1)
            a[m] = *reinterpret_cast<const bf16x8*>(
                xsb + kh * 6400 + wpos * 128 + (cb ^ FSWZ(wpos)));
        }
#pragma unroll
        for (int m = 0; m < 3; ++m)
#pragma unroll
            for (int n = 0; n < 4; ++n)
                acc[m][n] = __builtin_amdgcn_mfma_f32_16x16x32_bf16(
                    a[m], bfr[s & 3][n], acc[m][n], 0, 0, 0);
        if (s < 14) {                          // reload this bank with step s+4
            const int s4 = s + 4;
            const int off = (s4 >> 1) * 32 + (s4 & 1);
#pragma unroll
            for (int n = 0; n < 4; ++n)
                bfr[s & 3][n] = *reinterpret_cast<const bf16x8*>(
                    wbase + (off + n * 2) * 512);
        }
    }

    // ---- epilogue: plain float4 stores ----
#pragma unroll
    for (int m = 0; m < 3; ++m)
#pragma unroll
        for (int n = 0; n < 4; ++n) {
            int o = wn * 64 + n * 16 + l15;
            int w = ws + m * 16 + (lane >> 4) * 4;
            *reinterpret_cast<f32x4*>(
                out + (((size_t)(b * OO + o) * HH + h) * WW + w)) = acc[m][n];
        }
}

extern "C" void kernel_launch(void* const* d_in, const int* in_sizes, int n_in,
                              void* d_out, int out_size, void* d_ws, size_t ws_size,
                              hipStream_t stream) {
    const float* x     = (const float*)d_in[0];
    const float* dict  = (const float*)d_in[1];
    const float* coeff = (const float*)d_in[2];
    const int*   idx   = (const int*)d_in[3];
    float* out = (float*)d_out;

    char* ws = (char*)d_ws;
    unsigned short* weff2 = (unsigned short*)ws;               // 294912 B
    unsigned short* zbuf  = (unsigned short*)(ws + 294912);    // 16 B zeros
    unsigned short* x2    = (unsigned short*)(ws + 1048576);   // 18874368 B

    prep_kernel<<<NWG + OO, 256, 0, stream>>>(x, dict, coeff, idx, x2, weff2, zbuf);
    conv_kernel<<<NCV, 256, 0, stream>>>(x2, weff2, zbuf, out);
}